// Round 1
// 1204.226 us; speedup vs baseline: 1.0169x; 1.0169x over previous
//
#include <hip/hip_runtime.h>
#include <math.h>

#define BB 32
#define NN 1024
#define KNNK 20
#define PTS (BB*NN)   // 32768

typedef __attribute__((ext_vector_type(8)))  short short8;
typedef __attribute__((ext_vector_type(4)))  float f32x4;
typedef __attribute__((ext_vector_type(16))) float f32x16;

__device__ __forceinline__ float lrelu(float v){ return v >= 0.f ? v : 0.2f*v; }

__device__ __forceinline__ unsigned short f2b(float x){
    union { float f; unsigned u; } c; c.f = x;
    unsigned r = c.u + 0x7FFFu + ((c.u >> 16) & 1u);
    return (unsigned short)(r >> 16);
}

// ---------------- squared norms per point ----------------
__global__ void sq_kernel(const float* __restrict__ x, int stride, int C, float* __restrict__ xx){
    int pn = blockIdx.x*256 + threadIdx.x;
    if (pn >= PTS) return;
    const float* r = x + (size_t)pn*stride;
    float s = 0.f;
    for (int c = 0; c < C; ++c){ float v = r[c]; s = fmaf(v, v, s); }
    xx[pn] = s;
}

// ---------------- distance GEMM, SYMMETRIC: upper-tri 128x128 tiles, 8x8/thread ----------------
template<int C>
__global__ void __launch_bounds__(256) dist_kernel(const float* __restrict__ x, int stride,
                                                   const float* __restrict__ xx,
                                                   float* __restrict__ D, int b0){
    constexpr int KC = (C < 32 ? C : 32);
    __shared__ float As[KC][132];
    __shared__ float Bs[KC][132];
    const int tid = threadIdx.x;
    int t = blockIdx.x, ti = 0;
    while (t >= 8 - ti){ t -= 8 - ti; ++ti; }
    const int tj = ti + t;
    const int i0 = ti*128, j0 = tj*128;
    const int bl = blockIdx.z;
    const int b  = b0 + bl;
    const float* xb = x + (size_t)b*NN*stride;
    const int rt = tid >> 4, ct = tid & 15;
    float acc[8][8] = {{0.f}};

    for (int kc = 0; kc < C; kc += KC){
        __syncthreads();
        if constexpr (KC % 4 == 0){
            for (int i = tid; i < 128*(KC/4); i += 256){
                int kq = i % (KC/4), rr = i / (KC/4);
                float4 va = *(const float4*)&xb[(size_t)(i0+rr)*stride + kc + kq*4];
                As[kq*4+0][rr]=va.x; As[kq*4+1][rr]=va.y; As[kq*4+2][rr]=va.z; As[kq*4+3][rr]=va.w;
                float4 vb = *(const float4*)&xb[(size_t)(j0+rr)*stride + kc + kq*4];
                Bs[kq*4+0][rr]=vb.x; Bs[kq*4+1][rr]=vb.y; Bs[kq*4+2][rr]=vb.z; Bs[kq*4+3][rr]=vb.w;
            }
        } else {
            for (int i = tid; i < 128*KC; i += 256){
                int k = i % KC, rr = i / KC;
                As[k][rr] = xb[(size_t)(i0+rr)*stride + kc + k];
                Bs[k][rr] = xb[(size_t)(j0+rr)*stride + kc + k];
            }
        }
        __syncthreads();
        #pragma unroll
        for (int k = 0; k < KC; ++k){
            float4 a0 = *(const float4*)&As[k][rt*8];
            float4 a1 = *(const float4*)&As[k][rt*8+4];
            float4 b0v= *(const float4*)&Bs[k][ct*8];
            float4 b1v= *(const float4*)&Bs[k][ct*8+4];
            float av[8]={a0.x,a0.y,a0.z,a0.w,a1.x,a1.y,a1.z,a1.w};
            float bw[8]={b0v.x,b0v.y,b0v.z,b0v.w,b1v.x,b1v.y,b1v.z,b1v.w};
            #pragma unroll
            for (int i = 0; i < 8; ++i)
                #pragma unroll
                for (int j = 0; j < 8; ++j)
                    acc[i][j] = fmaf(av[i], bw[j], acc[i][j]);
        }
    }
    const float* xxb = xx + b*NN;
    float xi[8], xj[8];
    #pragma unroll
    for (int i=0;i<8;++i) xi[i] = xxb[i0 + rt*8 + i];
    #pragma unroll
    for (int j=0;j<8;++j) xj[j] = xxb[j0 + ct*8 + j];
    #pragma unroll
    for (int i=0;i<8;++i){
        float4 d0, d1;
        d0.x = 2.f*acc[i][0] - xi[i] - xj[0];
        d0.y = 2.f*acc[i][1] - xi[i] - xj[1];
        d0.z = 2.f*acc[i][2] - xi[i] - xj[2];
        d0.w = 2.f*acc[i][3] - xi[i] - xj[3];
        d1.x = 2.f*acc[i][4] - xi[i] - xj[4];
        d1.y = 2.f*acc[i][5] - xi[i] - xj[5];
        d1.z = 2.f*acc[i][6] - xi[i] - xj[6];
        d1.w = 2.f*acc[i][7] - xi[i] - xj[7];
        float* drow = &D[((size_t)bl*NN + i0 + rt*8 + i)*NN + j0 + ct*8];
        *(float4*)drow = d0;
        *(float4*)(drow+4) = d1;
    }
    if (ti != tj){
        #pragma unroll
        for (int j=0;j<8;++j){
            float4 m0, m1;
            m0.x = 2.f*acc[0][j] - xj[j] - xi[0];
            m0.y = 2.f*acc[1][j] - xj[j] - xi[1];
            m0.z = 2.f*acc[2][j] - xj[j] - xi[2];
            m0.w = 2.f*acc[3][j] - xj[j] - xi[3];
            m1.x = 2.f*acc[4][j] - xj[j] - xi[4];
            m1.y = 2.f*acc[5][j] - xj[j] - xi[5];
            m1.z = 2.f*acc[6][j] - xj[j] - xi[6];
            m1.w = 2.f*acc[7][j] - xj[j] - xi[7];
            float* mrow = &D[((size_t)bl*NN + j0 + ct*8 + j)*NN + i0 + rt*8];
            *(float4*)mrow = m0;
            *(float4*)(mrow+4) = m1;
        }
    }
}

// ---------------- top-k via radix bisection + ballot compaction (exact set, exact ties) ----
// wave per row. Selects {20 largest by (value desc, index asc)} — identical set to iterative
// argmax: all keys > t plus first (20-c) equals of t in ascending global index order.
// NOTE: tail emission loop is fully unrolled + predicated — a data-dependent `break` here
// made u[i] runtime-indexed and demoted u[] to scratch (VGPR_Count=20, 20ms profiled dur).
__global__ void __launch_bounds__(256) topk_kernel(const float* __restrict__ D,
                                                   int* __restrict__ idxout, int baseRow){
    const int tid = threadIdx.x;
    const int wv = tid >> 6, lane = tid & 63;
    const int rid = blockIdx.x*4 + wv;
    const float* drow = D + (size_t)rid * NN;
    unsigned u[16];
    #pragma unroll
    for (int i = 0; i < 16; ++i){
        unsigned bits = __float_as_uint(drow[i*64 + lane]);
        unsigned m = (bits & 0x80000000u) ? 0xFFFFFFFFu : 0x80000000u;  // monotone map
        u[i] = bits ^ m;
    }
    // bisect for t = 20th-largest key (max t with count(>= t) >= 20)
    unsigned t = 0u;
    for (int b = 31; b >= 0; --b){
        unsigned cand = t | (1u << b);
        int cnt = 0;
        #pragma unroll
        for (int i = 0; i < 16; ++i)
            cnt += (int)__popcll(__ballot(u[i] >= cand));
        if (cnt >= KNNK) t = cand;
    }
    const unsigned long long lt = (lane == 0) ? 0ull : ((~0ull) >> (64 - lane));
    int* orow = idxout + ((size_t)baseRow + rid) * KNNK;
    int cbase = 0;
    // emit all strictly greater (count <= 19 by construction of t)
    #pragma unroll
    for (int i = 0; i < 16; ++i){
        bool gt2 = (u[i] > t);
        unsigned long long mask = __ballot(gt2);
        if (gt2) orow[cbase + (int)__popcll(mask & lt)] = i*64 + lane;
        cbase += (int)__popcll(mask);
    }
    // fill remaining slots with equals in ascending global index (i asc, lane asc == j asc)
    // fully unrolled + predicated: once cbase >= 20 all stores predicate off.
    #pragma unroll
    for (int i = 0; i < 16; ++i){
        bool eq = (u[i] == t);
        unsigned long long mask = __ballot(eq);
        int pos = cbase + (int)__popcll(mask & lt);
        if (eq && pos < KNNK) orow[pos] = i*64 + lane;
        cbase += (int)__popcll(mask);
    }
}

// ---------------- G GEMMs: G1 = X @ W[:, :C]^T ; Gd = X @ (W[:,C:]-W[:, :C])^T ----------------
template<int C, int O>
__global__ void __launch_bounds__(256) gemmG_kernel(const float* __restrict__ x, int stride,
                                                    const float* __restrict__ W,
                                                    float* __restrict__ G1, float* __restrict__ Gd){
    constexpr int KC = (C < 32 ? C : 32);
    __shared__ float Xl [KC][68];
    __shared__ float W1l[KC][68];
    __shared__ float W2l[KC][68];
    const int tid = threadIdx.x;
    const int r0 = blockIdx.x * 64;
    const int o0 = blockIdx.y * 64;
    const int rt = tid & 15, ct = tid >> 4;

    float a1[4][4] = {{0.f}}, a2[4][4] = {{0.f}};
    for (int kc = 0; kc < C; kc += KC){
        __syncthreads();
        for (int i = tid; i < KC*64; i += 256){
            int k = i % KC, rr = i / KC;
            Xl [k][rr] = x[(size_t)(r0+rr)*stride + kc + k];
            W1l[k][rr] = W[(size_t)(o0+rr)*(2*C) + kc + k];
            W2l[k][rr] = W[(size_t)(o0+rr)*(2*C) + C + kc + k];
        }
        __syncthreads();
        #pragma unroll
        for (int k = 0; k < KC; ++k){
            float4 xa = *(const float4*)&Xl [k][rt*4];
            float4 w1 = *(const float4*)&W1l[k][ct*4];
            float4 w2 = *(const float4*)&W2l[k][ct*4];
            float xv[4] = {xa.x, xa.y, xa.z, xa.w};
            #pragma unroll
            for (int i = 0; i < 4; ++i){
                a1[i][0] = fmaf(xv[i], w1.x, a1[i][0]);
                a1[i][1] = fmaf(xv[i], w1.y, a1[i][1]);
                a1[i][2] = fmaf(xv[i], w1.z, a1[i][2]);
                a1[i][3] = fmaf(xv[i], w1.w, a1[i][3]);
                a2[i][0] = fmaf(xv[i], w2.x, a2[i][0]);
                a2[i][1] = fmaf(xv[i], w2.y, a2[i][1]);
                a2[i][2] = fmaf(xv[i], w2.z, a2[i][2]);
                a2[i][3] = fmaf(xv[i], w2.w, a2[i][3]);
            }
        }
    }
    #pragma unroll
    for (int i = 0; i < 4; ++i){
        size_t row = (size_t)(r0 + rt*4 + i);
        float4 g1v = make_float4(a1[i][0], a1[i][1], a1[i][2], a1[i][3]);
        float4 gdv = make_float4(a2[i][0]-a1[i][0], a2[i][1]-a1[i][1],
                                 a2[i][2]-a1[i][2], a2[i][3]-a1[i][3]);
        *(float4*)&G1[row*O + o0 + ct*4] = g1v;
        *(float4*)&Gd[row*O + o0 + ct*4] = gdv;
    }
}

// ---------------- gather (float4): per (point, 4 cols) max/sum/sumsq over k ----------------
// XCD-aware block swizzle: 64 consecutive logical blocks share one batch's G1/Gd slice
// (<=2MB, L2-resident). Default round-robin dispatch spreads them over all 8 XCDs ->
// each private L2 refetches the slice (FETCH ~225MB vs ~70MB ideal). Chunked bijection
// concentrates each batch onto one XCD.
template<int O>
__global__ void __launch_bounds__(256) gather_kernel(const float* __restrict__ G1,
                                                     const float* __restrict__ Gd,
                                                     const int* __restrict__ idxg, int bgbase,
                                                     float* __restrict__ catslice,
                                                     float* __restrict__ stats){
    constexpr int OG = O/4;
    constexpr int PP = 256/OG;
    constexpr int NP = 16;
    __shared__ int nbs[NP][KNNK];
    const int nwg = (int)gridDim.x;
    int bid = (int)blockIdx.x;
    if ((nwg & 7) == 0){
        const int cpx = nwg >> 3;
        bid = (bid & 7) * cpx + (bid >> 3);
    }
    const int tid = threadIdx.x;
    const int p0 = bid * NP;
    for (int i = tid; i < NP*KNNK; i += 256){
        int pp = i / KNNK, kk = i - pp*KNNK;
        int pl = p0 + pp;
        nbs[pp][kk] = ((pl >> 10) << 10) + idxg[(size_t)(bgbase + pl)*KNNK + kk];
    }
    __syncthreads();
    const int o4 = (tid % OG)*4;
    const int pq = tid / OG;
    float S1[4] = {0.f,0.f,0.f,0.f}, S2[4] = {0.f,0.f,0.f,0.f};
    for (int pp = pq; pp < NP; pp += PP){
        int pl = p0 + pp;
        float4 dv = *(const float4*)&Gd[(size_t)pl*O + o4];
        float d[4] = {dv.x, dv.y, dv.z, dv.w};
        float mx[4] = {-INFINITY,-INFINITY,-INFINITY,-INFINITY};
        float ls[4] = {0.f,0.f,0.f,0.f}, lq[4] = {0.f,0.f,0.f,0.f};
        #pragma unroll
        for (int kk = 0; kk < KNNK; ++kk){
            float4 gv = *(const float4*)&G1[(size_t)nbs[pp][kk]*O + o4];
            float ga[4] = {gv.x, gv.y, gv.z, gv.w};
            #pragma unroll
            for (int c = 0; c < 4; ++c){
                mx[c] = fmaxf(mx[c], ga[c]);
                ls[c] += ga[c];
                lq[c] = fmaf(ga[c], ga[c], lq[c]);
            }
        }
        float4 outv;
        float* op = &outv.x;
        #pragma unroll
        for (int c = 0; c < 4; ++c){
            S1[c] += ls[c] + 20.f*d[c];
            S2[c] += lq[c] + 2.f*d[c]*ls[c] + 20.f*d[c]*d[c];
            op[c] = mx[c] + d[c];
        }
        *(float4*)&catslice[(size_t)(bgbase + pl)*512 + o4] = outv;
    }
    int rep = bid & 63;
    #pragma unroll
    for (int c = 0; c < 4; ++c){
        atomicAdd(&stats[rep*2*O + o4 + c],     S1[c]);
        atomicAdd(&stats[rep*2*O + O + o4 + c], S2[c]);
    }
}

// ---------------- finalize BN stats ----------------
__global__ void fin_kernel(const float* __restrict__ stats, int O, float cnt,
                           float* __restrict__ mean, float* __restrict__ invstd){
    int o = threadIdx.x;
    if (o >= O) return;
    float s1 = 0.f, s2 = 0.f;
    for (int r = 0; r < 64; ++r){
        s1 += stats[r*2*O + o];
        s2 += stats[r*2*O + O + o];
    }
    float m = s1 / cnt;
    float v = s2 / cnt - m*m;
    mean[o] = m;
    invstd[o] = rsqrtf(v + 1e-5f);
}

// ---------------- apply BN+LReLU in place on cat slice ----------------
template<int O>
__global__ void apply_kernel(float* __restrict__ catslice,
                             const float* __restrict__ mean, const float* __restrict__ invstd,
                             const float* __restrict__ g, const float* __restrict__ bt){
    int i = blockIdx.x*256 + threadIdx.x;
    int pn = i / O, o = i - pn*O;
    float* p = &catslice[(size_t)pn*512 + o];
    float hn = (*p - mean[o]) * invstd[o] * g[o] + bt[o];
    *p = lrelu(hn);
}

// ---------------- fp32 -> bf16 conversion (4 elems/thread) ----------------
__global__ void tob16_kernel(const float* __restrict__ src, unsigned short* __restrict__ dst, int n4){
    int i = blockIdx.x*256 + threadIdx.x;
    if (i >= n4) return;
    float4 v = *(const float4*)&src[(size_t)i*4];
    ushort4 o;
    o.x = f2b(v.x); o.y = f2b(v.y); o.z = f2b(v.z); o.w = f2b(v.w);
    *(ushort4*)&dst[(size_t)i*4] = o;
}

// ---------------- layer 5 MFMA: 32x32x16 frags, 64x64/wave, 128x128/block ----------------
__global__ void __launch_bounds__(256) l5m_kernel(const unsigned short* __restrict__ Am,
                                                  const unsigned short* __restrict__ Bm,
                                                  float* __restrict__ pmax,
                                                  float* __restrict__ psum,
                                                  float* __restrict__ psq){
    __shared__ __align__(16) unsigned short As[128][64];
    __shared__ __align__(16) unsigned short Bs[128][64];
    const int tid = threadIdx.x;
    const int r0 = blockIdx.x * 128;
    const int o0 = blockIdx.y * 128;
    const int w = tid >> 6, lane = tid & 63;
    const int m32 = lane & 31, kh = lane >> 5;
    const int wm = (w & 1) * 64;
    const int wn = (w >> 1) * 64;

    f32x16 acc[2][2];
    #pragma unroll
    for (int i=0;i<2;++i)
        #pragma unroll
        for (int j=0;j<2;++j)
            #pragma unroll
            for (int r=0;r<16;++r) acc[i][j][r] = 0.f;

    for (int kc = 0; kc < 512; kc += 64){
        __syncthreads();
        #pragma unroll
        for (int t = 0; t < 4; ++t){
            int i = tid + t*256;
            int rr = i >> 3, ch = i & 7;
            int sl = ch ^ (rr & 7);
            *(uint4*)&As[rr][sl*8] = *(const uint4*)&Am[(size_t)(r0+rr)*512 + kc + ch*8];
            *(uint4*)&Bs[rr][sl*8] = *(const uint4*)&Bm[(size_t)(o0+rr)*512 + kc + ch*8];
        }
        __syncthreads();
        #pragma unroll
        for (int q = 0; q < 4; ++q){
            int lk = q*2 + kh;
            short8 a[2], bfr[2];
            #pragma unroll
            for (int mb = 0; mb < 2; ++mb){
                int rA = wm + mb*32 + m32;
                a[mb] = *(const short8*)&As[rA][(lk ^ (rA & 7))*8];
            }
            #pragma unroll
            for (int nb = 0; nb < 2; ++nb){
                int rB = wn + nb*32 + m32;
                bfr[nb] = *(const short8*)&Bs[rB][(lk ^ (rB & 7))*8];
            }
            #pragma unroll
            for (int mb = 0; mb < 2; ++mb)
                #pragma unroll
                for (int nb = 0; nb < 2; ++nb)
                    acc[mb][nb] = __builtin_amdgcn_mfma_f32_32x32x16_bf16(a[mb], bfr[nb], acc[mb][nb], 0, 0, 0);
        }
    }
    __syncthreads();
    float* red = (float*)&As[0][0];
    #pragma unroll
    for (int nb = 0; nb < 2; ++nb){
        float mx = -INFINITY, s1 = 0.f, s2 = 0.f;
        #pragma unroll
        for (int mb = 0; mb < 2; ++mb)
            #pragma unroll
            for (int r = 0; r < 16; ++r){
                float v = acc[mb][nb][r];
                mx = fmaxf(mx, v); s1 += v; s2 = fmaf(v, v, s2);
            }
        mx = fmaxf(mx, __shfl_xor(mx, 32));
        s1 += __shfl_xor(s1, 32);
        s2 += __shfl_xor(s2, 32);
        if (lane < 32){
            int col = wn + nb*32 + m32;
            float* p = red + ((size_t)(w & 1) * 128 + col) * 3;
            p[0] = mx; p[1] = s1; p[2] = s2;
        }
    }
    __syncthreads();
    if (tid < 128){
        const float* p0 = red + (size_t)tid*3;
        const float* p1 = red + (size_t)(128 + tid)*3;
        float mx = fmaxf(p0[0], p1[0]);
        float s1 = p0[1] + p1[1];
        float s2 = p0[2] + p1[2];
        size_t pi = (size_t)blockIdx.x*1024 + o0 + tid;
        pmax[pi] = mx; psum[pi] = s1; psq[pi] = s2;
    }
}

__global__ void fin5_kernel(const float* __restrict__ pmax, const float* __restrict__ psum,
                            const float* __restrict__ psq,
                            const float* __restrict__ g, const float* __restrict__ bt,
                            float* __restrict__ out){
    int o = blockIdx.x*256 + threadIdx.x; // 1024 total
    float s1 = 0.f, s2 = 0.f;
    for (int r = 0; r < 256; ++r){
        s1 += psum[(size_t)r*1024 + o];
        s2 += psq [(size_t)r*1024 + o];
    }
    float m  = s1 / 32768.f;
    float v  = s2 / 32768.f - m*m;
    float is = rsqrtf(v + 1e-5f);
    float gg = g[o], bb2 = bt[o];
    for (int b = 0; b < 32; ++b){
        float mx = -INFINITY;
        #pragma unroll
        for (int ns = 0; ns < 8; ++ns) mx = fmaxf(mx, pmax[((size_t)b*8 + ns)*1024 + o]);
        float hn = (mx - m) * is * gg + bb2;
        out[(size_t)b*1024 + o] = lrelu(hn);
    }
}

extern "C" void kernel_launch(void* const* d_in, const int* in_sizes, int n_in,
                              void* d_out, int out_size, void* d_ws, size_t ws_size,
                              hipStream_t stream) {
    (void)in_sizes; (void)n_in; (void)out_size;
    const float* x  = (const float*)d_in[0];
    const float* W1 = (const float*)d_in[1];  const float* g1 = (const float*)d_in[2];  const float* b1 = (const float*)d_in[3];
    const float* W2 = (const float*)d_in[4];  const float* g2 = (const float*)d_in[5];  const float* b2 = (const float*)d_in[6];
    const float* W3 = (const float*)d_in[7];  const float* g3 = (const float*)d_in[8];  const float* b3 = (const float*)d_in[9];
    const float* W4 = (const float*)d_in[10]; const float* g4 = (const float*)d_in[11]; const float* b4 = (const float*)d_in[12];
    const float* W5 = (const float*)d_in[13]; const float* g5 = (const float*)d_in[14]; const float* b5 = (const float*)d_in[15];
    float* out = (float*)d_out;

    const size_t fixedBytes = (size_t)PTS*512*4 + (size_t)PTS*KNNK*4 + (size_t)PTS*4
                            + (size_t)64*2*256*4 + 2048*4 + 3*(size_t)256*1024*4
                            + (size_t)1024*512*2;
    int CB;
    if      (ws_size >= fixedBytes + (size_t)32*NN*NN*4) CB = 32;
    else if (ws_size >= fixedBytes + (size_t)16*NN*NN*4) CB = 16;
    else                                                 CB = 8;
    const size_t Rbytes = (size_t)CB*NN*NN*4;

    char* wsp = (char*)d_ws;
    float* cat    = (float*)wsp; wsp += (size_t)PTS*512*4;
    char*  R      = wsp;         wsp += Rbytes;
    int*   idx    = (int*)  wsp; wsp += (size_t)PTS*KNNK*4;
    float* xx     = (float*)wsp; wsp += (size_t)PTS*4;
    float* stats  = (float*)wsp; wsp += (size_t)64*2*256*4;
    float* mean   = (float*)wsp; wsp += 1024*4;
    float* invstd = (float*)wsp; wsp += 1024*4;
    float* pmax   = (float*)wsp; wsp += (size_t)256*1024*4;
    float* psum   = (float*)wsp; wsp += (size_t)256*1024*4;
    float* psq    = (float*)wsp; wsp += (size_t)256*1024*4;
    unsigned short* W5b = (unsigned short*)wsp; wsp += (size_t)1024*512*2;

    float* Dbuf  = (float*)R;
    float* G1    = (float*)R;
    float* GdS   = (float*)(R + (size_t)16*1024*1024);
    float* GdB   = (float*)(R + (size_t)32*1024*1024);
    unsigned short* catB = (unsigned short*)R;

    const float cntE = (float)(PTS*KNNK);
    const int nch = 32 / CB;
    const bool bigG = (Rbytes >= (size_t)64*1024*1024);

    // ---- Layer 1: C=3 -> O=64 ----
    sq_kernel<<<PTS/256, 256, 0, stream>>>(x, 3, 3, xx);
    for (int bc = 0; bc < nch; ++bc){
        dist_kernel<3><<<dim3(36,1,CB), 256, 0, stream>>>(x, 3, xx, Dbuf, bc*CB);
        topk_kernel<<<CB*1024/4, 256, 0, stream>>>(Dbuf, idx, bc*CB*1024);
    }
    hipMemsetAsync(stats, 0, 64*2*256*4, stream);
    gemmG_kernel<3,64><<<dim3(512,1), 256, 0, stream>>>(x, 3, W1, G1, GdS);
    gather_kernel<64><<<2048, 256, 0, stream>>>(G1, GdS, idx, 0, cat + 0, stats);
    fin_kernel<<<1, 64, 0, stream>>>(stats, 64, cntE, mean, invstd);
    apply_kernel<64><<<PTS*64/256, 256, 0, stream>>>(cat + 0, mean, invstd, g1, b1);

    // ---- Layer 2: C=64 -> O=64 ----
    sq_kernel<<<PTS/256, 256, 0, stream>>>(cat + 0, 512, 64, xx);
    for (int bc = 0; bc < nch; ++bc){
        dist_kernel<64><<<dim3(36,1,CB), 256, 0, stream>>>(cat + 0, 512, xx, Dbuf, bc*CB);
        topk_kernel<<<CB*1024/4, 256, 0, stream>>>(Dbuf, idx, bc*CB*1024);
    }
    hipMemsetAsync(stats, 0, 64*2*256*4, stream);
    gemmG_kernel<64,64><<<dim3(512,1), 256, 0, stream>>>(cat + 0, 512, W2, G1, GdS);
    gather_kernel<64><<<2048, 256, 0, stream>>>(G1, GdS, idx, 0, cat + 64, stats);
    fin_kernel<<<1, 64, 0, stream>>>(stats, 64, cntE, mean, invstd);
    apply_kernel<64><<<PTS*64/256, 256, 0, stream>>>(cat + 64, mean, invstd, g2, b2);

    // ---- Layer 3: C=64 -> O=128 ----
    sq_kernel<<<PTS/256, 256, 0, stream>>>(cat + 64, 512, 64, xx);
    for (int bc = 0; bc < nch; ++bc){
        dist_kernel<64><<<dim3(36,1,CB), 256, 0, stream>>>(cat + 64, 512, xx, Dbuf, bc*CB);
        topk_kernel<<<CB*1024/4, 256, 0, stream>>>(Dbuf, idx, bc*CB*1024);
    }
    hipMemsetAsync(stats, 0, 64*2*256*4, stream);
    gemmG_kernel<64,128><<<dim3(512,2), 256, 0, stream>>>(cat + 64, 512, W3, G1, GdS);
    gather_kernel<128><<<2048, 256, 0, stream>>>(G1, GdS, idx, 0, cat + 128, stats);
    fin_kernel<<<1, 128, 0, stream>>>(stats, 128, cntE, mean, invstd);
    apply_kernel<128><<<PTS*128/256, 256, 0, stream>>>(cat + 128, mean, invstd, g3, b3);

    // ---- Layer 4: C=128 -> O=256 ----
    sq_kernel<<<PTS/256, 256, 0, stream>>>(cat + 128, 512, 128, xx);
    for (int bc = 0; bc < nch; ++bc){
        dist_kernel<128><<<dim3(36,1,CB), 256, 0, stream>>>(cat + 128, 512, xx, Dbuf, bc*CB);
        topk_kernel<<<CB*1024/4, 256, 0, stream>>>(Dbuf, idx, bc*CB*1024);
    }
    hipMemsetAsync(stats, 0, 64*2*256*4, stream);
    if (bigG){
        gemmG_kernel<128,256><<<dim3(512,4), 256, 0, stream>>>(cat + 128, 512, W4, G1, GdB);
        gather_kernel<256><<<2048, 256, 0, stream>>>(G1, GdB, idx, 0, cat + 256, stats);
    } else {
        for (int bg = 0; bg < 4; ++bg){
            gemmG_kernel<128,256><<<dim3(128,4), 256, 0, stream>>>(cat + 128 + (size_t)bg*8192*512, 512, W4, G1, GdS);
            gather_kernel<256><<<512, 256, 0, stream>>>(G1, GdS, idx, bg*8192, cat + 256, stats);
        }
    }
    fin_kernel<<<1, 256, 0, stream>>>(stats, 256, cntE, mean, invstd);
    apply_kernel<256><<<PTS*256/256, 256, 0, stream>>>(cat + 256, mean, invstd, g4, b4);

    // ---- Layer 5: bf16 MFMA GEMM with fused max/stats ----
    tob16_kernel<<<PTS*512/4/256, 256, 0, stream>>>(cat, catB, PTS*512/4);
    tob16_kernel<<<1024*512/4/256, 256, 0, stream>>>(W5, W5b, 1024*512/4);
    l5m_kernel<<<dim3(256, 8), 256, 0, stream>>>(catB, W5b, pmax, psum, psq);
    fin5_kernel<<<4, 256, 0, stream>>>(pmax, psum, psq, g5, b5, out);
}